// Round 1
// baseline (156.284 us; speedup 1.0000x reference)
//
#include <hip/hip_runtime.h>

// Problem constants (from reference): BZ=64, P=512, T=256, H=768
#define BZ 64
#define P  512
#define T  256
#define H  768
#define H4 (H / 4)   // 192 float4 per row

// Kernel 1: per-batch exclusive prefix sum of bert_lens -> start offsets.
// 64 blocks x 256 threads, Hillis-Steele scan in LDS.
__global__ void scan_kernel(const int* __restrict__ lens, int* __restrict__ starts) {
    __shared__ int sm[T];
    const int b = blockIdx.x;
    const int t = threadIdx.x;
    const int v = lens[b * T + t];
    sm[t] = v;
    __syncthreads();
    #pragma unroll
    for (int off = 1; off < T; off <<= 1) {
        const int add = (t >= off) ? sm[t - off] : 0;
        __syncthreads();
        sm[t] += add;
        __syncthreads();
    }
    starts[b * T + t] = sm[t] - v;  // exclusive prefix = first subword row of token t
}

// Kernel 2: one thread per output float4. Token t of batch b averages rows
// [start, start+len) of enc_out[b]; len==0 -> zeros.
__global__ void gather_kernel(const float* __restrict__ enc,
                              const int* __restrict__ lens,
                              const int* __restrict__ starts,
                              float* __restrict__ out) {
    const int idx = blockIdx.x * blockDim.x + threadIdx.x;  // [0, BZ*T*H4)
    const int h4  = idx % H4;
    const int bt  = idx / H4;       // [0, BZ*T) -- wave-uniform (192 % 64 == 0)
    const int b   = bt / T;

    const int len = lens[bt];
    float4 r = make_float4(0.f, 0.f, 0.f, 0.f);
    if (len > 0) {
        const int start = starts[bt];
        const float4* row =
            (const float4*)(enc + ((size_t)b * P + (size_t)start) * H) + h4;
        r = row[0];
        if (len > 1) {
            #pragma unroll 1
            for (int k = 1; k < len; ++k) {
                const float4 r2 = row[(size_t)k * H4];
                r.x += r2.x; r.y += r2.y; r.z += r2.z; r.w += r2.w;
            }
            const float inv = 1.0f / (float)len;
            r.x *= inv; r.y *= inv; r.z *= inv; r.w *= inv;
        }
    }
    ((float4*)out)[idx] = r;
}

extern "C" void kernel_launch(void* const* d_in, const int* in_sizes, int n_in,
                              void* d_out, int out_size, void* d_ws, size_t ws_size,
                              hipStream_t stream) {
    const float* enc   = (const float*)d_in[0];  // enc_out (BZ,P,H) f32
    // d_in[1] = bert_mask (unused; redundant with lens)
    const int*   lens  = (const int*)d_in[2];    // bert_lens (BZ,T) i32
    float*       out   = (float*)d_out;          // (BZ,T,H) f32
    int*         start = (int*)d_ws;             // (BZ,T) i32 scratch (64 KB)

    scan_kernel<<<BZ, T, 0, stream>>>(lens, start);

    const int total4 = BZ * T * H4;              // 3,145,728 float4 outputs
    gather_kernel<<<total4 / 256, 256, 0, stream>>>(enc, lens, start, out);
}